// Round 5
// baseline (307.102 us; speedup 1.0000x reference)
//
#include <hip/hip_runtime.h>
#include <stdint.h>

#define BATCH 4
#define TDIM 256
#define NPIX 4096
#define START 63
#define PLEN 193          // TDIM - START
#define THRESH 0.9f
#define ROUNDS 16

typedef unsigned long long u64;
typedef unsigned int uint32;
typedef float vfloat4 __attribute__((ext_vector_type(4)));  // native vec for nontemporal

// ---------------------------------------------------------------------------
// Kernel 1: per-pixel MLP features + L2-normalize. Weights fetched as
// wave-uniform scalar loads (SMEM path) — no LDS. Also init labels + flag.
// ---------------------------------------------------------------------------
__global__ __launch_bounds__(256) void feat_kernel(
    const float* __restrict__ spike, const float* __restrict__ w1,
    const float* __restrict__ b1, const float* __restrict__ w2,
    const float* __restrict__ b2, float* __restrict__ fn,
    int* __restrict__ labA, int* __restrict__ flag)
{
    const int g = blockIdx.x * 256 + threadIdx.x;  // 0..16383
    const int b = g >> 12;
    const int n = g & (NPIX - 1);
    const float* sp = spike + ((size_t)b * TDIM + START) * NPIX + n;
    const float4* w14 = (const float4*)w1;         // [PLEN][4 x float4]

    float h[16];
#pragma unroll
    for (int k = 0; k < 16; ++k) h[k] = 0.f;
#pragma unroll 2
    for (int t = 0; t < PLEN; ++t) {
        float x = sp[(size_t)t * NPIX];            // coalesced vector load
        float4 wa = w14[t * 4 + 0];                // uniform -> s_load
        float4 wb = w14[t * 4 + 1];
        float4 wc = w14[t * 4 + 2];
        float4 wd = w14[t * 4 + 3];
        h[0] = fmaf(x, wa.x, h[0]);  h[1] = fmaf(x, wa.y, h[1]);
        h[2] = fmaf(x, wa.z, h[2]);  h[3] = fmaf(x, wa.w, h[3]);
        h[4] = fmaf(x, wb.x, h[4]);  h[5] = fmaf(x, wb.y, h[5]);
        h[6] = fmaf(x, wb.z, h[6]);  h[7] = fmaf(x, wb.w, h[7]);
        h[8] = fmaf(x, wc.x, h[8]);  h[9] = fmaf(x, wc.y, h[9]);
        h[10] = fmaf(x, wc.z, h[10]); h[11] = fmaf(x, wc.w, h[11]);
        h[12] = fmaf(x, wd.x, h[12]); h[13] = fmaf(x, wd.y, h[13]);
        h[14] = fmaf(x, wd.z, h[14]); h[15] = fmaf(x, wd.w, h[15]);
    }
#pragma unroll
    for (int k = 0; k < 16; ++k) {
        float z = h[k] + b1[k];                    // uniform scalar load
        h[k] = z / (1.f + expf(-z));               // silu
    }
    float f[8];
#pragma unroll
    for (int m = 0; m < 8; ++m) f[m] = b2[m];
#pragma unroll
    for (int k = 0; k < 16; ++k) {
#pragma unroll
        for (int m = 0; m < 8; ++m)
            f[m] = fmaf(h[k], w2[k * 8 + m], f[m]); // uniform scalar loads
    }
#pragma unroll
    for (int m = 0; m < 8; ++m) f[m] = f[m] / (1.f + expf(-f[m]));  // silu
    float nrm = 0.f;
#pragma unroll
    for (int m = 0; m < 8; ++m) nrm = fmaf(f[m], f[m], nrm);
    nrm = fmaxf(sqrtf(nrm), 1e-6f);
#pragma unroll
    for (int m = 0; m < 8; ++m) f[m] = f[m] / nrm;

    float4* o4 = (float4*)(fn + (size_t)g * 8);
    o4[0] = make_float4(f[0], f[1], f[2], f[3]);
    o4[1] = make_float4(f[4], f[5], f[6], f[7]);

    labA[g] = n;                                   // identity labels (per batch)
    if (g == 0) *flag = 0;                         // convergence flag
}

// ---------------------------------------------------------------------------
// Kernel 2: adjacency bitmask. Block = 256 thr, handles batch b, 16 rows.
// ---------------------------------------------------------------------------
__global__ __launch_bounds__(256) void adj_kernel(
    const float* __restrict__ fn, u64* __restrict__ adj)
{
    __shared__ float s_fj[1024 * 8];               // 32 KiB
    const int b  = blockIdx.x >> 8;
    const int i0 = (blockIdx.x & 255) << 4;
    const int tid = threadIdx.x;
    const int wave = tid >> 6, lane = tid & 63;
    const float* fnb = fn + (size_t)b * NPIX * 8;

    float fi[4][8];                                // 4 rows per wave
#pragma unroll
    for (int r = 0; r < 4; ++r) {
        const float* src = fnb + (size_t)(i0 + wave * 4 + r) * 8;
#pragma unroll
        for (int e = 0; e < 8; ++e) fi[r][e] = src[e];
    }
    u64 saved[4] = {0, 0, 0, 0};                   // word 'lane' of each row

    for (int jc = 0; jc < 4; ++jc) {
        __syncthreads();
        const float4* src4 = (const float4*)(fnb + (size_t)jc * 1024 * 8);
        float4* dst4 = (float4*)s_fj;
#pragma unroll
        for (int q = 0; q < 8; ++q) dst4[q * 256 + tid] = src4[q * 256 + tid];
        __syncthreads();

        for (int ww = 0; ww < 16; ++ww) {
            const int jl = ww * 64 + lane;
            const float4* pj = (const float4*)(s_fj + jl * 8);
            float4 a = pj[0], c = pj[1];
            float fj[8] = {a.x, a.y, a.z, a.w, c.x, c.y, c.z, c.w};
            const int widx = jc * 16 + ww;
#pragma unroll
            for (int r = 0; r < 4; ++r) {
                float d = 0.f;
#pragma unroll
                for (int e = 0; e < 8; ++e) d = fmaf(fj[e], fi[r][e], d);
                u64 mask = __ballot(d >= THRESH);
                if (lane == widx) saved[r] = mask;
            }
        }
    }
    u64* adjbase = adj + ((size_t)b * NPIX + i0) * 64;
#pragma unroll
    for (int r = 0; r < 4; ++r)
        adjbase[(size_t)(wave * 4 + r) * 64 + lane] = saved[r];
}

// ---------------------------------------------------------------------------
// Kernel 3: one propagation round, jump FUSED. Stage src labels in LDS,
// build jmp[j] = src[clamp(src[j])] by LDS gather, then
// dst[i] = min over adj(i) of jmp[j]. 2 rows/wave, 8 rows/block.
// Early-exit via plain flag (kernel-boundary release/acquire).
// ---------------------------------------------------------------------------
__global__ __launch_bounds__(256) void min_kernel(
    const u64* __restrict__ adj, const int* __restrict__ src,
    int* __restrict__ dst, int* __restrict__ flag, int round)
{
    if (round > 0 && flag[0] < round) return;      // converged: labels final
    __shared__ int s_src[NPIX];                    // 16 KiB
    __shared__ int s_jmp[NPIX];                    // 16 KiB
    __shared__ int s_chg;
    const int tid = threadIdx.x;
    if (tid == 0) s_chg = 0;
    const int wave = tid >> 6, lane = tid & 63;
    const int row0 = blockIdx.x * 8 + wave * 2;    // global row, 2 rows/wave
    const int b = row0 >> 12;

    const int4* g4 = (const int4*)(src + (b << 12));
    int4* s4 = (int4*)s_src;
#pragma unroll
    for (int q = 0; q < 4; ++q) s4[q * 256 + tid] = g4[q * 256 + tid];
    __syncthreads();
#pragma unroll
    for (int q = 0; q < 16; ++q) {
        int j = q * 256 + tid;
        int v = s_src[j];
        s_jmp[j] = s_src[min(v, NPIX - 1)];        // fused pointer-jump (JAX clamp)
    }
    __syncthreads();

    const u64* arow = adj + (size_t)row0 * 64;
    const u64 wd0 = arow[lane];
    const u64 wd1 = arow[64 + lane];
    const uint32 lo0 = (uint32)wd0, hi0 = (uint32)(wd0 >> 32);
    const uint32 lo1 = (uint32)wd1, hi1 = (uint32)(wd1 >> 32);
    const uint32 lmask = 1u << (lane & 31);
    const bool hiHalf = lane >= 32;

    int m0 = NPIX, m1 = NPIX;                      // reference uses N as +inf
#pragma unroll 8
    for (int w = 0; w < 64; ++w) {
        const int lj = s_jmp[(w << 6) + lane];
        const uint32 ra0 = (uint32)__builtin_amdgcn_readlane((int)lo0, w);
        const uint32 rb0 = (uint32)__builtin_amdgcn_readlane((int)hi0, w);
        const uint32 ra1 = (uint32)__builtin_amdgcn_readlane((int)lo1, w);
        const uint32 rb1 = (uint32)__builtin_amdgcn_readlane((int)hi1, w);
        const uint32 h0 = hiHalf ? rb0 : ra0;
        const uint32 h1 = hiHalf ? rb1 : ra1;
        m0 = min(m0, (h0 & lmask) ? lj : NPIX);
        m1 = min(m1, (h1 & lmask) ? lj : NPIX);
    }
#pragma unroll
    for (int off = 32; off > 0; off >>= 1) {
        m0 = min(m0, __shfl_xor(m0, off));
        m1 = min(m1, __shfl_xor(m1, off));
    }

    const int i0 = row0 & (NPIX - 1);
    if (lane == 0) {
        dst[row0] = m0;
        dst[row0 + 1] = m1;
        if (m0 != s_src[i0] || m1 != s_src[i0 + 1]) s_chg = 1;
    }
    __syncthreads();
    if (tid == 0 && s_chg) *flag = round + 1;      // plain store, same value
}

// ---------------------------------------------------------------------------
// Kernel 4: final jump + is_root + cumsum rank + comp. One block per batch.
// ---------------------------------------------------------------------------
__global__ __launch_bounds__(256) void comp_kernel(
    const int* __restrict__ labsrc, int* __restrict__ comp)
{
    __shared__ int s_lab[NPIX];                    // 16 KiB
    __shared__ int s_rank[NPIX];                   // 16 KiB
    __shared__ int s_wsum[4];
    const int b = blockIdx.x, tid = threadIdx.x;
    const int* lb = labsrc + (b << 12);

    for (int i = tid; i < NPIX; i += 256) s_lab[i] = lb[i];
    __syncthreads();

    // final pointer-jump (reference: last op of each step is the jump)
    int regs[16];
#pragma unroll
    for (int k = 0; k < 16; ++k) {
        int i = k * 256 + tid;
        int v = s_lab[i];
        regs[k] = s_lab[min(v, NPIX - 1)];
    }
    __syncthreads();
#pragma unroll
    for (int k = 0; k < 16; ++k) s_lab[k * 256 + tid] = regs[k];
    __syncthreads();

    // inclusive cumsum of is_root, 16 contiguous elems per thread
    int loc[16];
    int sum = 0;
#pragma unroll
    for (int k = 0; k < 16; ++k) {
        int i = tid * 16 + k;
        sum += (s_lab[i] == i) ? 1 : 0;
        loc[k] = sum;
    }
    const int lane = tid & 63, wave = tid >> 6;
    int v = sum;
    for (int off = 1; off < 64; off <<= 1) {
        int u = __shfl_up(v, off);
        if (lane >= off) v += u;
    }
    if (lane == 63) s_wsum[wave] = v;
    __syncthreads();
    int waveoff = 0;
    for (int ww = 0; ww < 4; ++ww)
        if (ww < wave) waveoff += s_wsum[ww];
    const int excl = waveoff + v - sum;
#pragma unroll
    for (int k = 0; k < 16; ++k) s_rank[tid * 16 + k] = excl + loc[k] - 1;
    __syncthreads();

    int* cb = comp + (b << 12);
#pragma unroll
    for (int k = 0; k < 16; ++k) {
        int i = k * 256 + tid;
        cb[i] = s_rank[min(s_lab[i], NPIX - 1)];   // JAX clamp on rank[labels]
    }
}

// ---------------------------------------------------------------------------
// Kernel 5: write masks. out[b][r][p] = (comp[b][p] == r).
// 8 floats (2 x float4 nontemporal) per thread.
// ---------------------------------------------------------------------------
__global__ __launch_bounds__(256) void out_kernel(
    const int* __restrict__ comp, vfloat4* __restrict__ out)
{
    const int lin = blockIdx.x * 256 + threadIdx.x; // 0..2^23-1 (8-float chunks)
    const int p8 = lin & 511;
    const int r  = (lin >> 9) & 4095;
    const int b  = lin >> 21;
    const int4* cp = (const int4*)(comp + (b << 12) + (p8 << 3));
    const int4 c0 = cp[0];
    const int4 c1 = cp[1];
    vfloat4 v0, v1;
    v0.x = (c0.x == r) ? 1.f : 0.f;
    v0.y = (c0.y == r) ? 1.f : 0.f;
    v0.z = (c0.z == r) ? 1.f : 0.f;
    v0.w = (c0.w == r) ? 1.f : 0.f;
    v1.x = (c1.x == r) ? 1.f : 0.f;
    v1.y = (c1.y == r) ? 1.f : 0.f;
    v1.z = (c1.z == r) ? 1.f : 0.f;
    v1.w = (c1.w == r) ? 1.f : 0.f;
    __builtin_nontemporal_store(v0, out + (size_t)lin * 2);
    __builtin_nontemporal_store(v1, out + (size_t)lin * 2 + 1);
}

// ---------------------------------------------------------------------------
extern "C" void kernel_launch(void* const* d_in, const int* in_sizes, int n_in,
                              void* d_out, int out_size, void* d_ws, size_t ws_size,
                              hipStream_t stream)
{
    const float* spike = (const float*)d_in[0];
    const float* w1 = (const float*)d_in[1];
    const float* b1 = (const float*)d_in[2];
    const float* w2 = (const float*)d_in[3];
    const float* b2 = (const float*)d_in[4];

    // big scratch lives inside d_out (fully overwritten by out_kernel at end):
    //   [0, 8 MiB)          adjacency bitmask  (B*N rows x 64 u64 words)
    //   [8 MiB, 8.5 MiB)    fn features        (B*N x 8 f32)
    u64*   adj = (u64*)d_out;
    float* fn  = (float*)((char*)d_out + (size_t)8 * 1024 * 1024);
    // small state in d_ws (~196 KiB)
    int* labA = (int*)d_ws;
    int* labB = labA + BATCH * NPIX;
    int* comp = labB + BATCH * NPIX;
    int* flag = comp + BATCH * NPIX;

    feat_kernel<<<BATCH * NPIX / 256, 256, 0, stream>>>(spike, w1, b1, w2, b2,
                                                        fn, labA, flag);
    adj_kernel<<<BATCH * 256, 256, 0, stream>>>(fn, adj);

    int* bufs[2] = {labA, labB};
    for (int r = 0; r < ROUNDS; ++r)
        min_kernel<<<BATCH * NPIX / 8, 256, 0, stream>>>(adj, bufs[r & 1],
                                                         bufs[(r + 1) & 1], flag, r);

    comp_kernel<<<BATCH, 256, 0, stream>>>(bufs[ROUNDS & 1], comp);
    out_kernel<<<(BATCH * NPIX * NPIX / 8) / 256, 256, 0, stream>>>(
        comp, (vfloat4*)d_out);
}

// Round 6
// 294.894 us; speedup vs baseline: 1.0414x; 1.0414x over previous
//
#include <hip/hip_runtime.h>
#include <stdint.h>

#define BATCH 4
#define TDIM 256
#define NPIX 4096
#define START 63
#define PLEN 193          // TDIM - START
#define THRESH 0.9f
#define ROUNDS 16

typedef unsigned long long u64;
typedef unsigned int uint32;
typedef float vfloat4 __attribute__((ext_vector_type(4)));  // native vec for nontemporal

// ---------------------------------------------------------------------------
// Kernel 1: per-pixel MLP features + L2-normalize.
// 4-way t-split: each of 4 waves accumulates ~48 timesteps (partial h is
// linear), LDS reduce, wave 0 applies nonlinearity + norm. Loads issued in
// groups of 8 for memory-level parallelism (t-loop loads are independent).
// ---------------------------------------------------------------------------
__global__ __launch_bounds__(256) void feat_kernel(
    const float* __restrict__ spike, const float* __restrict__ w1,
    const float* __restrict__ b1, const float* __restrict__ w2,
    const float* __restrict__ b2, float* __restrict__ fn,
    int* __restrict__ labA, int* __restrict__ flag)
{
    __shared__ float s_part[3][64][17];            // +1 pad: conflict-free
    const int tid = threadIdx.x;
    const int lpix = tid & 63;
    const int q = tid >> 6;                        // wave = t-quarter
    const int g = blockIdx.x * 64 + lpix;          // 0..16383
    const int b = g >> 12;
    const int n = g & (NPIX - 1);
    const int t0 = q * 48;
    const int cnt = (q == 3) ? 49 : 48;            // 48*3 + 49 = 193
    const float* sp = spike + ((size_t)(b * TDIM + START + t0)) * NPIX + n;
    const float4* w14 = (const float4*)w1 + (size_t)t0 * 4;

    float h[16];
#pragma unroll
    for (int k = 0; k < 16; ++k) h[k] = 0.f;

    int i = 0;
    for (; i + 8 <= cnt; i += 8) {
        float x[8];
#pragma unroll
        for (int u = 0; u < 8; ++u) x[u] = sp[(size_t)(i + u) * NPIX];
#pragma unroll
        for (int u = 0; u < 8; ++u) {
            const float4 wa = w14[(i + u) * 4 + 0];   // uniform -> s_load
            const float4 wb = w14[(i + u) * 4 + 1];
            const float4 wc = w14[(i + u) * 4 + 2];
            const float4 wd = w14[(i + u) * 4 + 3];
            h[0] = fmaf(x[u], wa.x, h[0]);  h[1] = fmaf(x[u], wa.y, h[1]);
            h[2] = fmaf(x[u], wa.z, h[2]);  h[3] = fmaf(x[u], wa.w, h[3]);
            h[4] = fmaf(x[u], wb.x, h[4]);  h[5] = fmaf(x[u], wb.y, h[5]);
            h[6] = fmaf(x[u], wb.z, h[6]);  h[7] = fmaf(x[u], wb.w, h[7]);
            h[8] = fmaf(x[u], wc.x, h[8]);  h[9] = fmaf(x[u], wc.y, h[9]);
            h[10] = fmaf(x[u], wc.z, h[10]); h[11] = fmaf(x[u], wc.w, h[11]);
            h[12] = fmaf(x[u], wd.x, h[12]); h[13] = fmaf(x[u], wd.y, h[13]);
            h[14] = fmaf(x[u], wd.z, h[14]); h[15] = fmaf(x[u], wd.w, h[15]);
        }
    }
    for (; i < cnt; ++i) {
        float x = sp[(size_t)i * NPIX];
        const float4 wa = w14[i * 4 + 0];
        const float4 wb = w14[i * 4 + 1];
        const float4 wc = w14[i * 4 + 2];
        const float4 wd = w14[i * 4 + 3];
        h[0] = fmaf(x, wa.x, h[0]);  h[1] = fmaf(x, wa.y, h[1]);
        h[2] = fmaf(x, wa.z, h[2]);  h[3] = fmaf(x, wa.w, h[3]);
        h[4] = fmaf(x, wb.x, h[4]);  h[5] = fmaf(x, wb.y, h[5]);
        h[6] = fmaf(x, wb.z, h[6]);  h[7] = fmaf(x, wb.w, h[7]);
        h[8] = fmaf(x, wc.x, h[8]);  h[9] = fmaf(x, wc.y, h[9]);
        h[10] = fmaf(x, wc.z, h[10]); h[11] = fmaf(x, wc.w, h[11]);
        h[12] = fmaf(x, wd.x, h[12]); h[13] = fmaf(x, wd.y, h[13]);
        h[14] = fmaf(x, wd.z, h[14]); h[15] = fmaf(x, wd.w, h[15]);
    }

    if (q) {
#pragma unroll
        for (int k = 0; k < 16; ++k) s_part[q - 1][lpix][k] = h[k];
    }
    __syncthreads();
    if (q == 0) {
#pragma unroll
        for (int k = 0; k < 16; ++k)
            h[k] += s_part[0][lpix][k] + s_part[1][lpix][k] + s_part[2][lpix][k];
#pragma unroll
        for (int k = 0; k < 16; ++k) {
            float z = h[k] + b1[k];
            h[k] = z / (1.f + expf(-z));           // silu
        }
        float f[8];
#pragma unroll
        for (int m = 0; m < 8; ++m) f[m] = b2[m];
#pragma unroll
        for (int k = 0; k < 16; ++k) {
#pragma unroll
            for (int m = 0; m < 8; ++m)
                f[m] = fmaf(h[k], w2[k * 8 + m], f[m]);
        }
#pragma unroll
        for (int m = 0; m < 8; ++m) f[m] = f[m] / (1.f + expf(-f[m]));  // silu
        float nrm = 0.f;
#pragma unroll
        for (int m = 0; m < 8; ++m) nrm = fmaf(f[m], f[m], nrm);
        nrm = fmaxf(sqrtf(nrm), 1e-6f);
#pragma unroll
        for (int m = 0; m < 8; ++m) f[m] = f[m] / nrm;

        float4* o4 = (float4*)(fn + (size_t)g * 8);
        o4[0] = make_float4(f[0], f[1], f[2], f[3]);
        o4[1] = make_float4(f[4], f[5], f[6], f[7]);

        labA[g] = n;                               // identity labels (per batch)
        if (g == 0) *flag = 0;                     // convergence flag
    }
}

// ---------------------------------------------------------------------------
// Kernel 2: adjacency bitmask. Block = 256 thr, handles batch b, 16 rows.
// ---------------------------------------------------------------------------
__global__ __launch_bounds__(256) void adj_kernel(
    const float* __restrict__ fn, u64* __restrict__ adj)
{
    __shared__ float s_fj[1024 * 8];               // 32 KiB
    const int b  = blockIdx.x >> 8;
    const int i0 = (blockIdx.x & 255) << 4;
    const int tid = threadIdx.x;
    const int wave = tid >> 6, lane = tid & 63;
    const float* fnb = fn + (size_t)b * NPIX * 8;

    float fi[4][8];                                // 4 rows per wave
#pragma unroll
    for (int r = 0; r < 4; ++r) {
        const float* src = fnb + (size_t)(i0 + wave * 4 + r) * 8;
#pragma unroll
        for (int e = 0; e < 8; ++e) fi[r][e] = src[e];
    }
    u64 saved[4] = {0, 0, 0, 0};                   // word 'lane' of each row

    for (int jc = 0; jc < 4; ++jc) {
        __syncthreads();
        const float4* src4 = (const float4*)(fnb + (size_t)jc * 1024 * 8);
        float4* dst4 = (float4*)s_fj;
#pragma unroll
        for (int p = 0; p < 8; ++p) dst4[p * 256 + tid] = src4[p * 256 + tid];
        __syncthreads();

        for (int ww = 0; ww < 16; ++ww) {
            const int jl = ww * 64 + lane;
            const float4* pj = (const float4*)(s_fj + jl * 8);
            float4 a = pj[0], c = pj[1];
            float fj[8] = {a.x, a.y, a.z, a.w, c.x, c.y, c.z, c.w};
            const int widx = jc * 16 + ww;
#pragma unroll
            for (int r = 0; r < 4; ++r) {
                float d = 0.f;
#pragma unroll
                for (int e = 0; e < 8; ++e) d = fmaf(fj[e], fi[r][e], d);
                u64 mask = __ballot(d >= THRESH);
                if (lane == widx) saved[r] = mask;
            }
        }
    }
    u64* adjbase = adj + ((size_t)b * NPIX + i0) * 64;
#pragma unroll
    for (int r = 0; r < 4; ++r)
        adjbase[(size_t)(wave * 4 + r) * 64 + lane] = saved[r];
}

// ---------------------------------------------------------------------------
// Kernel 3: one propagation round = min-step composed with J^3 (triple
// pointer-jump), all in LDS. Valid because (i) J/M are monotone, so our
// trajectory pointwise dominates the reference's and both are >= the
// component-min fixed point F: equal to F by round<=13; (ii) we freeze only
// at fixed points, so the frozen state IS F. 32 rows/block, 8 rows/wave.
// ---------------------------------------------------------------------------
__global__ __launch_bounds__(256) void min_kernel(
    const u64* __restrict__ adj, const int* __restrict__ src,
    int* __restrict__ dst, int* __restrict__ flag, int round)
{
    if (round > 0 && flag[0] < round) return;      // converged: labels final
    __shared__ int sA[NPIX];                       // 16 KiB
    __shared__ int sB[NPIX];                       // 16 KiB
    __shared__ int s_chg;
    const int tid = threadIdx.x;
    if (tid == 0) s_chg = 0;
    const int wave = tid >> 6, lane = tid & 63;
    const int row0 = blockIdx.x * 32 + wave * 8;   // 8 rows per wave
    const int base = (row0 >> 12) << 12;           // batch base

    const int4* g4 = (const int4*)(src + base);
    int4* s4 = (int4*)sA;
#pragma unroll
    for (int p = 0; p < 4; ++p) s4[p * 256 + tid] = g4[p * 256 + tid];
    __syncthreads();
    // J^3 via LDS ping-pong (JAX OOB clamp each hop)
#pragma unroll
    for (int p = 0; p < 16; ++p) {
        int j = p * 256 + tid;
        sB[j] = sA[min(sA[j], NPIX - 1)];
    }
    __syncthreads();
#pragma unroll
    for (int p = 0; p < 16; ++p) {
        int j = p * 256 + tid;
        sA[j] = sB[min(sB[j], NPIX - 1)];
    }
    __syncthreads();
#pragma unroll
    for (int p = 0; p < 16; ++p) {
        int j = p * 256 + tid;
        sB[j] = sA[min(sA[j], NPIX - 1)];          // jmp = J^3(src) in sB
    }
    __syncthreads();

    const u64* arow = adj + (size_t)row0 * 64;
    uint32 lo[8], hi[8];
#pragma unroll
    for (int r = 0; r < 8; ++r) {
        u64 w = arow[(size_t)r * 64 + lane];
        lo[r] = (uint32)w; hi[r] = (uint32)(w >> 32);
    }
    const uint32 lmask = 1u << (lane & 31);
    const bool hiHalf = lane >= 32;

    int m[8];
#pragma unroll
    for (int r = 0; r < 8; ++r) m[r] = NPIX;       // reference uses N as +inf
#pragma unroll 4
    for (int w = 0; w < 64; ++w) {
        const int lj = sB[(w << 6) + lane];
#pragma unroll
        for (int r = 0; r < 8; ++r) {
            const uint32 a = (uint32)__builtin_amdgcn_readlane((int)lo[r], w);
            const uint32 c = (uint32)__builtin_amdgcn_readlane((int)hi[r], w);
            const uint32 hbits = hiHalf ? c : a;
            m[r] = min(m[r], (hbits & lmask) ? lj : NPIX);
        }
    }
#pragma unroll
    for (int off = 32; off > 0; off >>= 1) {
#pragma unroll
        for (int r = 0; r < 8; ++r) m[r] = min(m[r], __shfl_xor(m[r], off));
    }

    if (lane == 0) {
        bool chg = false;
#pragma unroll
        for (int r = 0; r < 8; ++r) {
            dst[row0 + r] = m[r];
            chg |= (m[r] != src[row0 + r]);
        }
        if (chg) s_chg = 1;
    }
    __syncthreads();
    if (tid == 0 && s_chg) *flag = round + 1;      // plain store, same value
}

// ---------------------------------------------------------------------------
// Kernel 4: final jump + is_root + cumsum rank + comp. One block per batch.
// ---------------------------------------------------------------------------
__global__ __launch_bounds__(256) void comp_kernel(
    const int* __restrict__ labsrc, int* __restrict__ comp)
{
    __shared__ int s_lab[NPIX];                    // 16 KiB
    __shared__ int s_rank[NPIX];                   // 16 KiB
    __shared__ int s_wsum[4];
    const int b = blockIdx.x, tid = threadIdx.x;
    const int* lb = labsrc + (b << 12);

    for (int i = tid; i < NPIX; i += 256) s_lab[i] = lb[i];
    __syncthreads();

    // final pointer-jump (identity at the fixed point; kept for exactness)
    int regs[16];
#pragma unroll
    for (int k = 0; k < 16; ++k) {
        int i = k * 256 + tid;
        int v = s_lab[i];
        regs[k] = s_lab[min(v, NPIX - 1)];
    }
    __syncthreads();
#pragma unroll
    for (int k = 0; k < 16; ++k) s_lab[k * 256 + tid] = regs[k];
    __syncthreads();

    // inclusive cumsum of is_root, 16 contiguous elems per thread
    int loc[16];
    int sum = 0;
#pragma unroll
    for (int k = 0; k < 16; ++k) {
        int i = tid * 16 + k;
        sum += (s_lab[i] == i) ? 1 : 0;
        loc[k] = sum;
    }
    const int lane = tid & 63, wave = tid >> 6;
    int v = sum;
    for (int off = 1; off < 64; off <<= 1) {
        int u = __shfl_up(v, off);
        if (lane >= off) v += u;
    }
    if (lane == 63) s_wsum[wave] = v;
    __syncthreads();
    int waveoff = 0;
    for (int ww = 0; ww < 4; ++ww)
        if (ww < wave) waveoff += s_wsum[ww];
    const int excl = waveoff + v - sum;
#pragma unroll
    for (int k = 0; k < 16; ++k) s_rank[tid * 16 + k] = excl + loc[k] - 1;
    __syncthreads();

    int* cb = comp + (b << 12);
#pragma unroll
    for (int k = 0; k < 16; ++k) {
        int i = k * 256 + tid;
        cb[i] = s_rank[min(s_lab[i], NPIX - 1)];   // JAX clamp on rank[labels]
    }
}

// ---------------------------------------------------------------------------
// Kernel 5: write masks. out[b][r][p] = (comp[b][p] == r).
// 8 floats (2 x float4 nontemporal) per thread.
// ---------------------------------------------------------------------------
__global__ __launch_bounds__(256) void out_kernel(
    const int* __restrict__ comp, vfloat4* __restrict__ out)
{
    const int lin = blockIdx.x * 256 + threadIdx.x; // 0..2^23-1 (8-float chunks)
    const int p8 = lin & 511;
    const int r  = (lin >> 9) & 4095;
    const int b  = lin >> 21;
    const int4* cp = (const int4*)(comp + (b << 12) + (p8 << 3));
    const int4 c0 = cp[0];
    const int4 c1 = cp[1];
    vfloat4 v0, v1;
    v0.x = (c0.x == r) ? 1.f : 0.f;
    v0.y = (c0.y == r) ? 1.f : 0.f;
    v0.z = (c0.z == r) ? 1.f : 0.f;
    v0.w = (c0.w == r) ? 1.f : 0.f;
    v1.x = (c1.x == r) ? 1.f : 0.f;
    v1.y = (c1.y == r) ? 1.f : 0.f;
    v1.z = (c1.z == r) ? 1.f : 0.f;
    v1.w = (c1.w == r) ? 1.f : 0.f;
    __builtin_nontemporal_store(v0, out + (size_t)lin * 2);
    __builtin_nontemporal_store(v1, out + (size_t)lin * 2 + 1);
}

// ---------------------------------------------------------------------------
extern "C" void kernel_launch(void* const* d_in, const int* in_sizes, int n_in,
                              void* d_out, int out_size, void* d_ws, size_t ws_size,
                              hipStream_t stream)
{
    const float* spike = (const float*)d_in[0];
    const float* w1 = (const float*)d_in[1];
    const float* b1 = (const float*)d_in[2];
    const float* w2 = (const float*)d_in[3];
    const float* b2 = (const float*)d_in[4];

    // big scratch lives inside d_out (fully overwritten by out_kernel at end):
    //   [0, 8 MiB)          adjacency bitmask  (B*N rows x 64 u64 words)
    //   [8 MiB, 8.5 MiB)    fn features        (B*N x 8 f32)
    u64*   adj = (u64*)d_out;
    float* fn  = (float*)((char*)d_out + (size_t)8 * 1024 * 1024);
    // small state in d_ws (~196 KiB)
    int* labA = (int*)d_ws;
    int* labB = labA + BATCH * NPIX;
    int* comp = labB + BATCH * NPIX;
    int* flag = comp + BATCH * NPIX;

    feat_kernel<<<BATCH * NPIX / 64, 256, 0, stream>>>(spike, w1, b1, w2, b2,
                                                       fn, labA, flag);
    adj_kernel<<<BATCH * 256, 256, 0, stream>>>(fn, adj);

    int* bufs[2] = {labA, labB};
    for (int r = 0; r < ROUNDS; ++r)
        min_kernel<<<BATCH * NPIX / 32, 256, 0, stream>>>(adj, bufs[r & 1],
                                                          bufs[(r + 1) & 1], flag, r);

    comp_kernel<<<BATCH, 256, 0, stream>>>(bufs[ROUNDS & 1], comp);
    out_kernel<<<(BATCH * NPIX * NPIX / 8) / 256, 256, 0, stream>>>(
        comp, (vfloat4*)d_out);
}